// Round 4
// baseline (153.672 us; speedup 1.0000x reference)
//
#include <hip/hip_runtime.h>

// Problem constants (fixed by reference)
#define D_DIRS 1024
#define P_PTS  256
#define R_RANK 64
#define K_SUB  1024

typedef float v4f __attribute__((ext_vector_type(4)));

// Workspace layout in floats (1 MiB used):
//   a[D][R]            @ 0          -- consumed by k_partial_m
//   b[D][R]            @ 65536
//   Mpart[32][64][64]  @ 131072
//   Msum[64][64]       @ 0          -- OVERLAPS a (written strictly after
//                                      k_partial_m consumed a; same stream).
#define WS_A 0
#define WS_B (D_DIRS * R_RANK)
#define WS_M (2 * D_DIRS * R_RANK)
#define WS_MSUM 0
#define NB_B 32
#define DCHUNK (D_DIRS / NB_B) // 32

__device__ __forceinline__ v4f ntload(const v4f* __restrict__ p) {
    return __builtin_nontemporal_load(p);
}

__device__ __forceinline__ v4f shfl_xor_v4(v4f v, int m) {
    v4f r;
    r.x = __shfl_xor(v.x, m);
    r.y = __shfl_xor(v.y, m);
    r.z = __shfl_xor(v.z, m);
    r.w = __shfl_xor(v.w, m);
    return r;
}

// ---------------------------------------------------------------------------
// Kernel 1: p-reduction.  a[d,r] = sum_p atten[d,p,r]; b likewise.
// R4: fat-block streaming. 256 blocks (1/CU) x 512 threads; block owns 4
// CONSECUTIVE d-slabs (256 KB contiguous per array) -> 512 long streams
// instead of 2048 short ones (R2/R3 plateaued at ~3.5 TB/s with TLP and MLP
// both maxed; stream/row locality is the remaining theory).
// 2-deep pipeline: d+1's 16 loads issue before d's reduction, so the waits
// are partial (vmcnt(N)) and BW never idles during the shuffle/LDS phase.
// Thread t covers slab float4 index t + k*512, k<8 (wave = 1 KiB coalesced).
// Reduction: lanes ^16/^32 share r-group -> 2 shuffle rounds, then one
// barrier and an 8-way LDS sum by 16 lanes per array (waves 0 and 1 work
// on A and B in parallel).
// ---------------------------------------------------------------------------
__global__ __launch_bounds__(512) void k_reduce_p(const float* __restrict__ atten,
                                                  const float* __restrict__ rad,
                                                  float* __restrict__ ws) {
    const int bid  = blockIdx.x;   // 0..255
    const int t    = threadIdx.x;  // 0..511
    const int lane = t & 63;
    const int wave = t >> 6;       // 0..7
    const int rq   = t & 15;       // float4 group of r (t == pg*16+rq)

    const v4f* A4 = (const v4f*)atten;
    const v4f* B4 = (const v4f*)rad;

    __shared__ v4f lA[2][8][16]; // [parity][wave][rq], 4 KiB
    __shared__ v4f lB[2][8][16]; // 4 KiB

    const int d0 = bid * 4;

    v4f a_cur[8], b_cur[8], a_nxt[8], b_nxt[8];
    {
        const v4f* pa = A4 + (size_t)d0 * 4096 + t;
        const v4f* pb = B4 + (size_t)d0 * 4096 + t;
#pragma unroll
        for (int k = 0; k < 8; ++k) a_cur[k] = ntload(pa + k * 512);
#pragma unroll
        for (int k = 0; k < 8; ++k) b_cur[k] = ntload(pb + k * 512);
    }

#pragma unroll
    for (int dd = 0; dd < 4; ++dd) {
        const int d = d0 + dd;

        // Prefetch the next slab before touching cur (partial vmcnt waits).
        if (dd < 3) {
            const v4f* na = A4 + (size_t)(d + 1) * 4096 + t;
            const v4f* nb = B4 + (size_t)(d + 1) * 4096 + t;
#pragma unroll
            for (int k = 0; k < 8; ++k) a_nxt[k] = ntload(na + k * 512);
#pragma unroll
            for (int k = 0; k < 8; ++k) b_nxt[k] = ntload(nb + k * 512);
        }

        // Pairwise tree over the 8 p-samples this thread owns.
        v4f sa = ((a_cur[0] + a_cur[1]) + (a_cur[2] + a_cur[3])) +
                 ((a_cur[4] + a_cur[5]) + (a_cur[6] + a_cur[7]));
        v4f sb = ((b_cur[0] + b_cur[1]) + (b_cur[2] + b_cur[3])) +
                 ((b_cur[4] + b_cur[5]) + (b_cur[6] + b_cur[7]));

        // Lanes lane, lane^16, lane^32, lane^48 share rq.
        sa = sa + shfl_xor_v4(sa, 16);
        sa = sa + shfl_xor_v4(sa, 32);
        sb = sb + shfl_xor_v4(sb, 16);
        sb = sb + shfl_xor_v4(sb, 32);

        if ((lane >> 4) == 0) { // lanes 0..15 hold the wave partial
            lA[dd & 1][wave][rq] = sa;
            lB[dd & 1][wave][rq] = sb;
        }
        __syncthreads();

        if (t < 16) {
            v4f s = lA[dd & 1][0][t];
#pragma unroll
            for (int w = 1; w < 8; ++w) s = s + lA[dd & 1][w][t];
            ((v4f*)(ws + WS_A))[d * 16 + t] = s;
        } else if (t >= 64 && t < 80) {
            const int q = t - 64;
            v4f s = lB[dd & 1][0][q];
#pragma unroll
            for (int w = 1; w < 8; ++w) s = s + lB[dd & 1][w][q];
            ((v4f*)(ws + WS_B))[d * 16 + q] = s;
        }
        // Parity double-buffer: dd+2 reuses this LDS slot, but dd+1's
        // __syncthreads sits in between -> safe without a second barrier.

#pragma unroll
        for (int k = 0; k < 8; ++k) { a_cur[k] = a_nxt[k]; b_cur[k] = b_nxt[k]; }
    }
}

// ---------------------------------------------------------------------------
// Kernel 2: partial M.  Block bb covers d in [bb*32, bb*32+32), all (r,r').
// a-row reads are wave-uniform (broadcast); b reads stride-1 (2-way, free).
// ---------------------------------------------------------------------------
__global__ __launch_bounds__(256) void k_partial_m(float* __restrict__ ws) {
    const int bb = blockIdx.x;
    const int t  = threadIdx.x;

    __shared__ float sa[DCHUNK * R_RANK]; // 8 KiB
    __shared__ float sb[DCHUNK * R_RANK]; // 8 KiB

    const float4* a4 = (const float4*)(ws + WS_A) + bb * (DCHUNK * R_RANK / 4);
    const float4* b4 = (const float4*)(ws + WS_B) + bb * (DCHUNK * R_RANK / 4);
    float4* sa4 = (float4*)sa;
    float4* sb4 = (float4*)sb;
    sa4[t]       = a4[t];
    sa4[t + 256] = a4[t + 256];
    sb4[t]       = b4[t];
    sb4[t + 256] = b4[t + 256];
    __syncthreads();

    const int c  = t & 63;
    const int wg = t >> 6;

    float acc[16];
#pragma unroll
    for (int i = 0; i < 16; ++i) acc[i] = 0.f;

    for (int dd = 0; dd < DCHUNK; ++dd) {
        const float bv = sb[dd * 64 + c];
        const float4* ar = (const float4*)&sa[dd * 64 + wg * 16];
        const float4 a0 = ar[0], a1 = ar[1], a2 = ar[2], a3 = ar[3];
        acc[0]  += a0.x * bv; acc[1]  += a0.y * bv; acc[2]  += a0.z * bv; acc[3]  += a0.w * bv;
        acc[4]  += a1.x * bv; acc[5]  += a1.y * bv; acc[6]  += a1.z * bv; acc[7]  += a1.w * bv;
        acc[8]  += a2.x * bv; acc[9]  += a2.y * bv; acc[10] += a2.z * bv; acc[11] += a2.w * bv;
        acc[12] += a3.x * bv; acc[13] += a3.y * bv; acc[14] += a3.z * bv; acc[15] += a3.w * bv;
    }

    float* Mp = ws + WS_M + bb * 4096;
#pragma unroll
    for (int i = 0; i < 16; ++i) Mp[(wg * 16 + i) * 64 + c] = acc[i];
}

// ---------------------------------------------------------------------------
// Kernel 3: reduce the 32 partial Ms -> Msum (4096 floats @ ws[0]).
// ---------------------------------------------------------------------------
__global__ __launch_bounds__(256) void k_reduce_m(float* __restrict__ ws) {
    const int tg = blockIdx.x * 256 + threadIdx.x; // float4 column 0..1023
    const float4* Mp4 = (const float4*)(ws + WS_M);
    float4 s = make_float4(0.f, 0.f, 0.f, 0.f);
#pragma unroll
    for (int g = 0; g < NB_B; ++g) {
        const float4 v = Mp4[g * 1024 + tg];
        s.x += v.x; s.y += v.y; s.z += v.z; s.w += v.w;
    }
    ((float4*)(ws + WS_MSUM))[tg] = s;
}

// ---------------------------------------------------------------------------
// Kernel 4: csi[k] = (1/D) F[k] Msum F[k]^T.
// ---------------------------------------------------------------------------
__global__ __launch_bounds__(256) void k_csi(const float* __restrict__ ws,
                                             const float* __restrict__ freq,
                                             float* __restrict__ out) {
    const int bb = blockIdx.x;
    const int t  = threadIdx.x;

    __shared__ float Ms[64 * 68];   // ~17 KiB
    __shared__ float Fs[64 * 65];   // ~16.6 KiB
    __shared__ float red[4][64];

    const float4* M4 = (const float4*)(ws + WS_MSUM);
#pragma unroll
    for (int i = 0; i < 4; ++i) {
        const int idx4 = i * 256 + t;
        const float4 s = M4[idx4];
        const int r = idx4 >> 4, c4 = idx4 & 15;
        *(float4*)&Ms[r * 68 + c4 * 4] = s;
    }

    const float4* F4 = (const float4*)freq + bb * 1024;
#pragma unroll
    for (int i = 0; i < 4; ++i) {
        const int idx4 = i * 256 + t;
        const float4 v = F4[idx4];
        const int row = idx4 >> 4, c4 = idx4 & 15;
        Fs[row * 65 + c4 * 4 + 0] = v.x;
        Fs[row * 65 + c4 * 4 + 1] = v.y;
        Fs[row * 65 + c4 * 4 + 2] = v.z;
        Fs[row * 65 + c4 * 4 + 3] = v.w;
    }
    __syncthreads();

    const int kl = t & 63;
    const int jg = t >> 6;

    float h[16];
#pragma unroll
    for (int j = 0; j < 16; ++j) h[j] = 0.f;

    for (int r = 0; r < 64; ++r) {
        const float fv = Fs[kl * 65 + r];
        const float4* mr = (const float4*)&Ms[r * 68 + jg * 16];
        const float4 m0 = mr[0], m1 = mr[1], m2 = mr[2], m3 = mr[3];
        h[0]  += fv * m0.x; h[1]  += fv * m0.y; h[2]  += fv * m0.z; h[3]  += fv * m0.w;
        h[4]  += fv * m1.x; h[5]  += fv * m1.y; h[6]  += fv * m1.z; h[7]  += fv * m1.w;
        h[8]  += fv * m2.x; h[9]  += fv * m2.y; h[10] += fv * m2.z; h[11] += fv * m2.w;
        h[12] += fv * m3.x; h[13] += fv * m3.y; h[14] += fv * m3.z; h[15] += fv * m3.w;
    }

    float part = 0.f;
#pragma unroll
    for (int j = 0; j < 16; ++j) part += h[j] * Fs[kl * 65 + jg * 16 + j];

    red[jg][kl] = part;
    __syncthreads();
    if (t < 64) {
        out[bb * 64 + t] =
            (red[0][t] + red[1][t] + red[2][t] + red[3][t]) * (1.0f / (float)D_DIRS);
    }
}

extern "C" void kernel_launch(void* const* d_in, const int* in_sizes, int n_in,
                              void* d_out, int out_size, void* d_ws, size_t ws_size,
                              hipStream_t stream) {
    const float* atten = (const float*)d_in[0]; // (D,P,R)
    const float* rad   = (const float*)d_in[1]; // (D,P,R)
    const float* freq  = (const float*)d_in[2]; // (K,R)
    float* out = (float*)d_out;                 // (K,)
    float* ws  = (float*)d_ws;

    k_reduce_p<<<D_DIRS / 4, 512, 0, stream>>>(atten, rad, ws);
    k_partial_m<<<NB_B, 256, 0, stream>>>(ws);
    k_reduce_m<<<4, 256, 0, stream>>>(ws);
    k_csi<<<16, 256, 0, stream>>>(ws, freq, out);
}

// Round 5
// 149.405 us; speedup vs baseline: 1.0286x; 1.0286x over previous
//
#include <hip/hip_runtime.h>

// Problem constants (fixed by reference)
#define D_DIRS 1024
#define P_PTS  256
#define R_RANK 64
#define K_SUB  1024

typedef float v4f __attribute__((ext_vector_type(4)));

// Workspace layout in floats (1 MiB used):
//   a[D][R]            @ 0          -- consumed by k_partial_m
//   b[D][R]            @ 65536
//   Mpart[32][64][64]  @ 131072
//   Msum[64][64]       @ 0          -- OVERLAPS a (written strictly after
//                                      k_partial_m consumed a; same stream).
#define WS_A 0
#define WS_B (D_DIRS * R_RANK)
#define WS_M (2 * D_DIRS * R_RANK)
#define WS_MSUM 0
#define NB_B 32
#define DCHUNK (D_DIRS / NB_B) // 32

__device__ __forceinline__ v4f ntload(const v4f* __restrict__ p) {
    return __builtin_nontemporal_load(p);
}

__device__ __forceinline__ v4f shfl_xor_v4(v4f v, int m) {
    v4f r;
    r.x = __shfl_xor(v.x, m);
    r.y = __shfl_xor(v.y, m);
    r.z = __shfl_xor(v.z, m);
    r.w = __shfl_xor(v.w, m);
    return r;
}

// ---------------------------------------------------------------------------
// Kernel 1: p-reduction.  a[d,r] = sum_p atten[d,p,r]; b likewise.
// R5: BARRIER-FREE wave-private streaming. R1-R4 all plateaued at 3.0-3.6
// TB/s read; their common trait was a block-wide __syncthreads reduction tree
// per d, draining all outstanding loads (vmcnt(0) before s_barrier). Here
// each wave owns (d, half-slab): no LDS, no barriers, loads outstanding
// continuously via a 2-deep 8-load-chunk pipeline, reduction via 3 in-register
// shfl_xor rounds.
//   grid 256 blocks x 512 threads = 2048 waves = 1024 d x 2 halves.
//   wave w of block b: d = 4b + (w>>1), half = w&1.
//   lane l: r4g = l&7 (float4-group in half), pr = l>>3 (p-row offset).
//   chunk c (0..31): float4 addr = d*4096 + c*128 + pr*16 + half*8 + r4g
//     -> wave-instr = 8 p-rows x 128 B aligned segments, fully coalesced.
//   lane's r4 identity is c-invariant -> accumulate, then reduce over pr
//   (xor 8,16,32), lanes 0..7 store the 128-B half-row of a[d] (b likewise).
// ---------------------------------------------------------------------------
__global__ __launch_bounds__(512) void k_reduce_p(const float* __restrict__ atten,
                                                  const float* __restrict__ rad,
                                                  float* __restrict__ ws) {
    const int t    = threadIdx.x;
    const int wave = t >> 6;
    const int lane = t & 63;
    const int d    = blockIdx.x * 4 + (wave >> 1);
    const int half = wave & 1;
    const int r4g  = lane & 7;
    const int pr   = lane >> 3;

    const int base = pr * 16 + half * 8 + r4g; // within-slab float4 offset, c=0
    const v4f* A4 = (const v4f*)atten + (size_t)d * 4096 + base;
    const v4f* B4 = (const v4f*)rad   + (size_t)d * 4096 + base;

    v4f pa[8], pb[8], na[8], nb[8];
#pragma unroll
    for (int j = 0; j < 8; ++j) pa[j] = ntload(A4 + j * 128);
#pragma unroll
    for (int j = 0; j < 8; ++j) pb[j] = ntload(B4 + j * 128);

    v4f acc_a = {0.f, 0.f, 0.f, 0.f};
    v4f acc_b = {0.f, 0.f, 0.f, 0.f};

#pragma unroll
    for (int mc = 0; mc < 4; ++mc) {
        if (mc < 3) {
            const int off = (mc + 1) * 8 * 128;
#pragma unroll
            for (int j = 0; j < 8; ++j) na[j] = ntload(A4 + off + j * 128);
#pragma unroll
            for (int j = 0; j < 8; ++j) nb[j] = ntload(B4 + off + j * 128);
        }
        // Pairwise tree over this chunk's 8 p-rows.
        acc_a = acc_a + (((pa[0] + pa[1]) + (pa[2] + pa[3])) +
                         ((pa[4] + pa[5]) + (pa[6] + pa[7])));
        acc_b = acc_b + (((pb[0] + pb[1]) + (pb[2] + pb[3])) +
                         ((pb[4] + pb[5]) + (pb[6] + pb[7])));
#pragma unroll
        for (int j = 0; j < 8; ++j) { pa[j] = na[j]; pb[j] = nb[j]; }
    }

    // Reduce across pr (lanes sharing r4g): xor 8, 16, 32. No barriers.
    acc_a = acc_a + shfl_xor_v4(acc_a, 8);
    acc_a = acc_a + shfl_xor_v4(acc_a, 16);
    acc_a = acc_a + shfl_xor_v4(acc_a, 32);
    acc_b = acc_b + shfl_xor_v4(acc_b, 8);
    acc_b = acc_b + shfl_xor_v4(acc_b, 16);
    acc_b = acc_b + shfl_xor_v4(acc_b, 32);

    if (pr == 0) { // lanes 0..7
        ((v4f*)(ws + WS_A))[d * 16 + half * 8 + r4g] = acc_a;
        ((v4f*)(ws + WS_B))[d * 16 + half * 8 + r4g] = acc_b;
    }
}

// ---------------------------------------------------------------------------
// Kernel 2: partial M.  Block bb covers d in [bb*32, bb*32+32), all (r,r').
// a-row reads are wave-uniform (broadcast); b reads stride-1 (2-way, free).
// ---------------------------------------------------------------------------
__global__ __launch_bounds__(256) void k_partial_m(float* __restrict__ ws) {
    const int bb = blockIdx.x;
    const int t  = threadIdx.x;

    __shared__ float sa[DCHUNK * R_RANK]; // 8 KiB
    __shared__ float sb[DCHUNK * R_RANK]; // 8 KiB

    const float4* a4 = (const float4*)(ws + WS_A) + bb * (DCHUNK * R_RANK / 4);
    const float4* b4 = (const float4*)(ws + WS_B) + bb * (DCHUNK * R_RANK / 4);
    float4* sa4 = (float4*)sa;
    float4* sb4 = (float4*)sb;
    sa4[t]       = a4[t];
    sa4[t + 256] = a4[t + 256];
    sb4[t]       = b4[t];
    sb4[t + 256] = b4[t + 256];
    __syncthreads();

    const int c  = t & 63;
    const int wg = t >> 6;

    float acc[16];
#pragma unroll
    for (int i = 0; i < 16; ++i) acc[i] = 0.f;

    for (int dd = 0; dd < DCHUNK; ++dd) {
        const float bv = sb[dd * 64 + c];
        const float4* ar = (const float4*)&sa[dd * 64 + wg * 16];
        const float4 a0 = ar[0], a1 = ar[1], a2 = ar[2], a3 = ar[3];
        acc[0]  += a0.x * bv; acc[1]  += a0.y * bv; acc[2]  += a0.z * bv; acc[3]  += a0.w * bv;
        acc[4]  += a1.x * bv; acc[5]  += a1.y * bv; acc[6]  += a1.z * bv; acc[7]  += a1.w * bv;
        acc[8]  += a2.x * bv; acc[9]  += a2.y * bv; acc[10] += a2.z * bv; acc[11] += a2.w * bv;
        acc[12] += a3.x * bv; acc[13] += a3.y * bv; acc[14] += a3.z * bv; acc[15] += a3.w * bv;
    }

    float* Mp = ws + WS_M + bb * 4096;
#pragma unroll
    for (int i = 0; i < 16; ++i) Mp[(wg * 16 + i) * 64 + c] = acc[i];
}

// ---------------------------------------------------------------------------
// Kernel 3: reduce the 32 partial Ms -> Msum (4096 floats @ ws[0]).
// ---------------------------------------------------------------------------
__global__ __launch_bounds__(256) void k_reduce_m(float* __restrict__ ws) {
    const int tg = blockIdx.x * 256 + threadIdx.x; // float4 column 0..1023
    const float4* Mp4 = (const float4*)(ws + WS_M);
    float4 s = make_float4(0.f, 0.f, 0.f, 0.f);
#pragma unroll
    for (int g = 0; g < NB_B; ++g) {
        const float4 v = Mp4[g * 1024 + tg];
        s.x += v.x; s.y += v.y; s.z += v.z; s.w += v.w;
    }
    ((float4*)(ws + WS_MSUM))[tg] = s;
}

// ---------------------------------------------------------------------------
// Kernel 4: csi[k] = (1/D) F[k] Msum F[k]^T.
// ---------------------------------------------------------------------------
__global__ __launch_bounds__(256) void k_csi(const float* __restrict__ ws,
                                             const float* __restrict__ freq,
                                             float* __restrict__ out) {
    const int bb = blockIdx.x;
    const int t  = threadIdx.x;

    __shared__ float Ms[64 * 68];   // ~17 KiB
    __shared__ float Fs[64 * 65];   // ~16.6 KiB
    __shared__ float red[4][64];

    const float4* M4 = (const float4*)(ws + WS_MSUM);
#pragma unroll
    for (int i = 0; i < 4; ++i) {
        const int idx4 = i * 256 + t;
        const float4 s = M4[idx4];
        const int r = idx4 >> 4, c4 = idx4 & 15;
        *(float4*)&Ms[r * 68 + c4 * 4] = s;
    }

    const float4* F4 = (const float4*)freq + bb * 1024;
#pragma unroll
    for (int i = 0; i < 4; ++i) {
        const int idx4 = i * 256 + t;
        const float4 v = F4[idx4];
        const int row = idx4 >> 4, c4 = idx4 & 15;
        Fs[row * 65 + c4 * 4 + 0] = v.x;
        Fs[row * 65 + c4 * 4 + 1] = v.y;
        Fs[row * 65 + c4 * 4 + 2] = v.z;
        Fs[row * 65 + c4 * 4 + 3] = v.w;
    }
    __syncthreads();

    const int kl = t & 63;
    const int jg = t >> 6;

    float h[16];
#pragma unroll
    for (int j = 0; j < 16; ++j) h[j] = 0.f;

    for (int r = 0; r < 64; ++r) {
        const float fv = Fs[kl * 65 + r];
        const float4* mr = (const float4*)&Ms[r * 68 + jg * 16];
        const float4 m0 = mr[0], m1 = mr[1], m2 = mr[2], m3 = mr[3];
        h[0]  += fv * m0.x; h[1]  += fv * m0.y; h[2]  += fv * m0.z; h[3]  += fv * m0.w;
        h[4]  += fv * m1.x; h[5]  += fv * m1.y; h[6]  += fv * m1.z; h[7]  += fv * m1.w;
        h[8]  += fv * m2.x; h[9]  += fv * m2.y; h[10] += fv * m2.z; h[11] += fv * m2.w;
        h[12] += fv * m3.x; h[13] += fv * m3.y; h[14] += fv * m3.z; h[15] += fv * m3.w;
    }

    float part = 0.f;
#pragma unroll
    for (int j = 0; j < 16; ++j) part += h[j] * Fs[kl * 65 + jg * 16 + j];

    red[jg][kl] = part;
    __syncthreads();
    if (t < 64) {
        out[bb * 64 + t] =
            (red[0][t] + red[1][t] + red[2][t] + red[3][t]) * (1.0f / (float)D_DIRS);
    }
}

extern "C" void kernel_launch(void* const* d_in, const int* in_sizes, int n_in,
                              void* d_out, int out_size, void* d_ws, size_t ws_size,
                              hipStream_t stream) {
    const float* atten = (const float*)d_in[0]; // (D,P,R)
    const float* rad   = (const float*)d_in[1]; // (D,P,R)
    const float* freq  = (const float*)d_in[2]; // (K,R)
    float* out = (float*)d_out;                 // (K,)
    float* ws  = (float*)d_ws;

    k_reduce_p<<<D_DIRS / 4, 512, 0, stream>>>(atten, rad, ws);
    k_partial_m<<<NB_B, 256, 0, stream>>>(ws);
    k_reduce_m<<<4, 256, 0, stream>>>(ws);
    k_csi<<<16, 256, 0, stream>>>(ws, freq, out);
}